// Round 2
// baseline (199.826 us; speedup 1.0000x reference)
//
#include <hip/hip_runtime.h>
#include <math.h>

#define B_  4
#define V_  256
#define C1_ 64
#define C2_ 32
#define H0_ 128
#define H2_ 256

typedef short bf16x8 __attribute__((ext_vector_type(8)));
typedef short s16x4  __attribute__((ext_vector_type(4)));
typedef float f32x4  __attribute__((ext_vector_type(4)));

static __device__ __forceinline__ short f2bf(float f) {
    unsigned u = __float_as_uint(f);
    u += 0x7fffu + ((u >> 16) & 1u);          // RNE
    return (short)(u >> 16);
}

// ---------------------------------------------------------------------------
// Weight prep (runs every launch): transpose + bf16-convert the edge-part of
// W1 (W1c: [32][H0] -> [H0][32]) and W2 ([H0][H0] -> [H0][H0]^T) for both
// conv layers, so MFMA B-fragments are contiguous 16 B loads.
// Layout in wsW (shorts): W1cT1[128*32] | W2T1[128*128] | W1cT2 | W2T2
// ---------------------------------------------------------------------------
__global__ __launch_bounds__(256) void prep_k(
    const float* __restrict__ W1c1, const float* __restrict__ W21,
    const float* __restrict__ W1c2, const float* __restrict__ W22,
    short* __restrict__ wsW)
{
    int idx = blockIdx.x * 256 + threadIdx.x;        // 40960 total
    if (idx < 4096) {
        int n = idx >> 5, k = idx & 31;
        wsW[idx] = f2bf(W1c1[k * H0_ + n]);
    } else if (idx < 20480) {
        int t = idx - 4096; int n = t >> 7, k = t & 127;
        wsW[idx] = f2bf(W21[k * H0_ + n]);
    } else if (idx < 24576) {
        int t = idx - 20480; int n = t >> 5, k = t & 31;
        wsW[idx] = f2bf(W1c2[k * H0_ + n]);
    } else if (idx < 40960) {
        int t = idx - 24576; int n = t >> 7, k = t & 127;
        wsW[idx] = f2bf(W22[k * H0_ + n]);
    }
}

// ---------------------------------------------------------------------------
// Per-node hoist: P = x@(W1a-W1b)+b1, Q = x@W1b (fp32, unchanged)
// ---------------------------------------------------------------------------
template <int CIN>
__global__ __launch_bounds__(128) void node_pre_k(
    const float* __restrict__ x, const float* __restrict__ W1,
    const float* __restrict__ b1, float* __restrict__ P, float* __restrict__ Q)
{
    const int bi = blockIdx.x, n = threadIdx.x;
    __shared__ __align__(16) float s_x[CIN];
    if (n < CIN) s_x[n] = x[bi * CIN + n];
    __syncthreads();
    float accP = b1[n], accQ = 0.f;
    #pragma unroll 4
    for (int k = 0; k < CIN; k += 4) {
        float4 xv = *reinterpret_cast<const float4*>(&s_x[k]);
        float wa0 = W1[(k + 0) * H0_ + n], wb0 = W1[(CIN + k + 0) * H0_ + n];
        float wa1 = W1[(k + 1) * H0_ + n], wb1 = W1[(CIN + k + 1) * H0_ + n];
        float wa2 = W1[(k + 2) * H0_ + n], wb2 = W1[(CIN + k + 2) * H0_ + n];
        float wa3 = W1[(k + 3) * H0_ + n], wb3 = W1[(CIN + k + 3) * H0_ + n];
        accP = fmaf(xv.x, wa0 - wb0, accP);  accQ = fmaf(xv.x, wb0, accQ);
        accP = fmaf(xv.y, wa1 - wb1, accP);  accQ = fmaf(xv.y, wb1, accQ);
        accP = fmaf(xv.z, wa2 - wb2, accP);  accQ = fmaf(xv.z, wb2, accQ);
        accP = fmaf(xv.w, wa3 - wb3, accP);  accQ = fmaf(xv.w, wb3, accQ);
    }
    P[bi * H0_ + n] = accP;
    Q[bi * H0_ + n] = accQ;
}

// ---------------------------------------------------------------------------
// EdgeConvE main, MFMA v3: transposed GEMM1 + double-buffered h1.
// Block = node (b,i); 4 waves.
// GEMM1 per pass of 64 edges: wave w owns edges row0..row0+15 as the *columns*
//   of a swapped MFMA:  h1^T = W1c^T (A-op) x e^T (B-op).  The A/B fragment
//   layouts of 16x16x32 are symmetric, so the same two fragments as before
//   are passed in swapped order.  Output: acc'[nt][r] = channel nt*16+quad*4+r
//   of edge row0+l15  -> each lane owns 4 CONTIGUOUS channels of ONE edge:
//     * Q gather:  8 float4 loads (was 32 scalar)
//     * P:         8 float4 loads
//     * LDS write: 8 ds_write_b64 of packed bf16 quads (was 32 ds_write_b16)
//   and the e-row index and Q-row index are the same lane value (one s_list
//   lookup serves both).
// GEMM2: N-split across waves (B2 = 32 VGPRs), M = all 64 rows from LDS.
// s_h1 is double-buffered -> ONE barrier per pass (pass p+2's overwrite of
// buf[p&1] is fenced by pass p+1's barrier, which every wave reaches only
// after finishing pass p's GEMM2 reads).
// ---------------------------------------------------------------------------
__global__ __launch_bounds__(256, 4) void conv_mfma_k(
    const int* __restrict__ adj, const float* __restrict__ e,
    const float* __restrict__ P, const float* __restrict__ Q,
    const short* __restrict__ W1cT, const short* __restrict__ W2T,
    const float* __restrict__ b2, float* __restrict__ out)
{
    const int bi   = blockIdx.x;           // b*V + i
    const int b    = bi >> 8;
    const int tid  = threadIdx.x;
    const int w    = tid >> 6;
    const int lane = tid & 63;
    const int l15  = lane & 15;
    const int quad = lane >> 4;

    __shared__ int s_list[V_];
    __shared__ int s_cnt;
    __shared__ __align__(16) short s_h1[2][64][136];   // 272 B stride, 16B-aligned

    if (tid == 0) s_cnt = 0;
    __syncthreads();
    if (adj[bi * V_ + tid] > 0) { int p = atomicAdd(&s_cnt, 1); s_list[p] = tid; }
    __syncthreads();
    const int cnt = s_cnt;
    if (cnt == 0) { if (tid < H0_) out[bi * H0_ + tid] = 0.f; return; }

    // GEMM2 B-fragments: wave w owns N-tiles 2w, 2w+1 (8 frags = 32 VGPR)
    bf16x8 B2[2][4];
    float bb[2], vmax[2];
    #pragma unroll
    for (int h = 0; h < 2; ++h) {
        const int nt = w * 2 + h;
        #pragma unroll
        for (int kk = 0; kk < 4; ++kk)
            B2[h][kk] = *(const bf16x8*)(W2T + (nt * 16 + l15) * H0_ + kk * 32 + quad * 8);
        bb[h]   = b2[nt * 16 + l15];
        vmax[h] = 0.f;
    }

    const int row0 = w * 16;
    const float* Prow = P + bi * H0_;

    // prefetch first pass: this lane's edge (serves both e-row and Q-row)
    int ta0 = row0 + l15; if (ta0 >= cnt) ta0 = cnt - 1;
    int jcur = s_list[ta0];
    {
    }
    const float* er0 = e + (bi * V_ + jcur) * C2_ + quad * 8;
    float4 e0 = *(const float4*)(er0);
    float4 e1 = *(const float4*)(er0 + 4);

    int pb = 0;
    for (int t0 = 0; t0 < cnt; t0 += 64) {
        // B-operand of swapped GEMM1: e[edge=l15][k=quad*8+j]
        bf16x8 A1;
        A1[0] = f2bf(e0.x); A1[1] = f2bf(e0.y); A1[2] = f2bf(e0.z); A1[3] = f2bf(e0.w);
        A1[4] = f2bf(e1.x); A1[5] = f2bf(e1.y); A1[6] = f2bf(e1.z); A1[7] = f2bf(e1.w);
        const int jrow = jcur;

        // issue next pass's e loads; they retire under GEMM1+GEMM2
        {
            int tn = t0 + 64 + row0 + l15; if (tn >= cnt) tn = cnt - 1;
            jcur = s_list[tn];
            const float* ern = e + (bi * V_ + jcur) * C2_ + quad * 8;
            e0 = *(const float4*)(ern);
            e1 = *(const float4*)(ern + 4);
        }

        const float* Qrow = Q + (b * V_ + jrow) * H0_;

        // GEMM1 + epilogue in two nt-halves (caps live acc at 16 VGPRs)
        #pragma unroll
        for (int hf = 0; hf < 2; ++hf) {
            f32x4 acc[4];
            #pragma unroll
            for (int q4 = 0; q4 < 4; ++q4) {
                const int nt = hf * 4 + q4;
                bf16x8 Bw = *(const bf16x8*)(W1cT + (nt * 16 + l15) * C2_ + quad * 8);
                f32x4 z = {0.f, 0.f, 0.f, 0.f};
                // swapped operands: A = W1c^T, B = e^T  ->  C = h1^T
                acc[q4] = __builtin_amdgcn_mfma_f32_16x16x32_bf16(Bw, A1, z, 0, 0, 0);
            }
            #pragma unroll
            for (int q4 = 0; q4 < 4; ++q4) {
                const int nt = hf * 4 + q4;
                const int ch = nt * 16 + quad * 4;
                float4 Pv = *(const float4*)(Prow + ch);
                float4 Qv = *(const float4*)(Qrow + ch);
                s16x4 sv;
                sv.x = f2bf(fmaxf(acc[q4][0] + Pv.x + Qv.x, 0.f));
                sv.y = f2bf(fmaxf(acc[q4][1] + Pv.y + Qv.y, 0.f));
                sv.z = f2bf(fmaxf(acc[q4][2] + Pv.z + Qv.z, 0.f));
                sv.w = f2bf(fmaxf(acc[q4][3] + Pv.w + Qv.w, 0.f));
                *(s16x4*)(&s_h1[pb][row0 + l15][ch]) = sv;
            }
        }

        __syncthreads();

        // GEMM2: h1 @ W2, N-split across waves, M = all 64 edge rows
        #pragma unroll
        for (int mt = 0; mt < 4; ++mt) {
            f32x4 a20 = {0.f,0.f,0.f,0.f}, a21 = {0.f,0.f,0.f,0.f};
            #pragma unroll
            for (int kk = 0; kk < 4; ++kk) {
                bf16x8 A2 = *(const bf16x8*)(&s_h1[pb][mt * 16 + l15][kk * 32 + quad * 8]);
                a20 = __builtin_amdgcn_mfma_f32_16x16x32_bf16(A2, B2[0][kk], a20, 0, 0, 0);
                a21 = __builtin_amdgcn_mfma_f32_16x16x32_bf16(A2, B2[1][kk], a21, 0, 0, 0);
            }
            float m0 = fmaxf(fmaxf(a20[0], a20[1]), fmaxf(a20[2], a20[3]));
            float m1 = fmaxf(fmaxf(a21[0], a21[1]), fmaxf(a21[2], a21[3]));
            vmax[0] = fmaxf(vmax[0], fmaxf(m0 + bb[0], 0.f));
            vmax[1] = fmaxf(vmax[1], fmaxf(m1 + bb[1], 0.f));
        }
        pb ^= 1;
    }

    // cross-quad (rows) max, then direct write of this wave's own channels
    #pragma unroll
    for (int h = 0; h < 2; ++h) {
        float p = vmax[h];
        p = fmaxf(p, __shfl_xor(p, 16, 64));
        p = fmaxf(p, __shfl_xor(p, 32, 64));
        if (quad == 0) out[bi * H0_ + (w * 2 + h) * 16 + l15] = p;
    }
}

// ---------------------------------------------------------------------------
// Pair hoist (fp32, unchanged): Ai = x2@W3[H0:]+b3, Aj = x2@W3[:H0]
// ---------------------------------------------------------------------------
__global__ __launch_bounds__(256) void pair_pre_k(
    const float* __restrict__ x2, const float* __restrict__ W3,
    const float* __restrict__ b3, float* __restrict__ Ai, float* __restrict__ Aj)
{
    const int bi = blockIdx.x, n = threadIdx.x;
    __shared__ __align__(16) float s_x[H0_];
    if (n < H0_) s_x[n] = x2[bi * H0_ + n];
    __syncthreads();
    float aI = b3[n], aJ = 0.f;
    #pragma unroll 4
    for (int k = 0; k < H0_; k += 4) {
        float4 xv = *reinterpret_cast<const float4*>(&s_x[k]);
        aJ = fmaf(xv.x, W3[(k + 0) * H2_ + n], aJ);
        aJ = fmaf(xv.y, W3[(k + 1) * H2_ + n], aJ);
        aJ = fmaf(xv.z, W3[(k + 2) * H2_ + n], aJ);
        aJ = fmaf(xv.w, W3[(k + 3) * H2_ + n], aJ);
        aI = fmaf(xv.x, W3[(H0_ + k + 0) * H2_ + n], aI);
        aI = fmaf(xv.y, W3[(H0_ + k + 1) * H2_ + n], aI);
        aI = fmaf(xv.z, W3[(H0_ + k + 2) * H2_ + n], aI);
        aI = fmaf(xv.w, W3[(H0_ + k + 3) * H2_ + n], aI);
    }
    Ai[bi * H2_ + n] = aI;
    Aj[bi * H2_ + n] = aJ;
}

// ---------------------------------------------------------------------------
// Pair output v3: j-range split 4-ways -> 1024 blocks. Block = (b, 4
// consecutive i, j-quarter); wave = one i over 64 j's.
// ---------------------------------------------------------------------------
__global__ __launch_bounds__(256) void pair_out_k(
    const float* __restrict__ Ai, const float* __restrict__ Aj,
    const float* __restrict__ Wo, const float* __restrict__ bo,
    float* __restrict__ out)
{
    const int blk  = blockIdx.x;                       // 1024 blocks
    const int b    = blk >> 8;
    const int ig   = (blk >> 2) & 63;
    const int jq   = blk & 3;
    const int i    = (ig << 2) + (threadIdx.x >> 6);
    const int lane = threadIdx.x & 63;
    const int jj   = lane >> 4;
    const int c    = lane & 15;

    const float* ai = Ai + (b * V_ + i) * H2_ + c * 16;
    float4 a0 = *(const float4*)(ai);
    float4 a1 = *(const float4*)(ai + 4);
    float4 a2 = *(const float4*)(ai + 8);
    float4 a3 = *(const float4*)(ai + 12);
    const float* wo = Wo + c * 16;
    float4 w0 = *(const float4*)(wo);
    float4 w1 = *(const float4*)(wo + 4);
    float4 w2 = *(const float4*)(wo + 8);
    float4 w3 = *(const float4*)(wo + 12);
    const float bo0 = bo[0];

    const int jbase = jq * 64;
    for (int j0 = jbase; j0 < jbase + 64; j0 += 4) {
        const int j = j0 + jj;
        const float* aj = Aj + (b * V_ + j) * H2_ + c * 16;
        float4 q0 = *(const float4*)(aj);
        float4 q1 = *(const float4*)(aj + 4);
        float4 q2 = *(const float4*)(aj + 8);
        float4 q3 = *(const float4*)(aj + 12);
        float p;
        p = fmaxf(a0.x + q0.x, 0.f) * w0.x;
        p = fmaf(fmaxf(a0.y + q0.y, 0.f), w0.y, p);
        p = fmaf(fmaxf(a0.z + q0.z, 0.f), w0.z, p);
        p = fmaf(fmaxf(a0.w + q0.w, 0.f), w0.w, p);
        p = fmaf(fmaxf(a1.x + q1.x, 0.f), w1.x, p);
        p = fmaf(fmaxf(a1.y + q1.y, 0.f), w1.y, p);
        p = fmaf(fmaxf(a1.z + q1.z, 0.f), w1.z, p);
        p = fmaf(fmaxf(a1.w + q1.w, 0.f), w1.w, p);
        p = fmaf(fmaxf(a2.x + q2.x, 0.f), w2.x, p);
        p = fmaf(fmaxf(a2.y + q2.y, 0.f), w2.y, p);
        p = fmaf(fmaxf(a2.z + q2.z, 0.f), w2.z, p);
        p = fmaf(fmaxf(a2.w + q2.w, 0.f), w2.w, p);
        p = fmaf(fmaxf(a3.x + q3.x, 0.f), w3.x, p);
        p = fmaf(fmaxf(a3.y + q3.y, 0.f), w3.y, p);
        p = fmaf(fmaxf(a3.z + q3.z, 0.f), w3.z, p);
        p = fmaf(fmaxf(a3.w + q3.w, 0.f), w3.w, p);
        #pragma unroll
        for (int off = 1; off < 16; off <<= 1)
            p += __shfl_xor(p, off, 64);               // stays within jj group
        if (c == 0)
            out[(b * V_ + i) * V_ + j] = 1.f / (1.f + __builtin_expf(-(p + bo0)));
    }
}

// ---------------------------------------------------------------------------
extern "C" void kernel_launch(void* const* d_in, const int* in_sizes, int n_in,
                              void* d_out, int out_size, void* d_ws, size_t ws_size,
                              hipStream_t stream) {
    const int*   adj   = (const int*)  d_in[0];
    const float* xf    = (const float*)d_in[1];
    const float* ea    = (const float*)d_in[2];
    const float* ec1W1 = (const float*)d_in[3];
    const float* ec1b1 = (const float*)d_in[4];
    const float* ec1W2 = (const float*)d_in[5];
    const float* ec1b2 = (const float*)d_in[6];
    const float* ec2W1 = (const float*)d_in[7];
    const float* ec2b1 = (const float*)d_in[8];
    const float* ec2W2 = (const float*)d_in[9];
    const float* ec2b2 = (const float*)d_in[10];
    const float* h3W   = (const float*)d_in[11];
    const float* h3b   = (const float*)d_in[12];
    const float* oW    = (const float*)d_in[13];
    const float* ob    = (const float*)d_in[14];
    float* out = (float*)d_out;

    const int NV = B_ * V_;                    // 1024 nodes
    float* x1 = (float*)d_ws;                  // NV*H0
    float* x2 = x1 + NV * H0_;                 // NV*H0
    float* R  = x2 + NV * H0_;                 // reuse region
    float* P  = R;                             // NV*H0
    float* Q  = R + NV * H0_;                  // NV*H0
    float* Ai = R;                             // NV*H2 (P/Q dead by then)
    float* Aj = R + NV * H2_;                  // NV*H2
    short* wsW = (short*)(R + 2 * NV * H2_);   // 40960 bf16 weights
    short* W1cT1 = wsW;
    short* W2T1  = wsW + 4096;
    short* W1cT2 = wsW + 20480;
    short* W2T2  = wsW + 24576;

    prep_k<<<160, 256, 0, stream>>>(ec1W1 + 2 * C1_ * H0_, ec1W2,
                                    ec2W1 + 2 * H0_ * H0_, ec2W2, wsW);
    // conv1
    node_pre_k<C1_><<<NV, 128, 0, stream>>>(xf, ec1W1, ec1b1, P, Q);
    conv_mfma_k<<<NV, 256, 0, stream>>>(adj, ea, P, Q, W1cT1, W2T1, ec1b2, x1);
    // conv2
    node_pre_k<H0_><<<NV, 128, 0, stream>>>(x1, ec2W1, ec2b1, P, Q);
    conv_mfma_k<<<NV, 256, 0, stream>>>(adj, ea, P, Q, W1cT2, W2T2, ec2b2, x2);
    // pair scoring
    pair_pre_k<<<NV, 256, 0, stream>>>(x2, h3W, h3b, Ai, Aj);
    pair_out_k<<<B_ * V_, 256, 0, stream>>>(Ai, Aj, oW, ob, out);
}

// Round 3
// 189.807 us; speedup vs baseline: 1.0528x; 1.0528x over previous
//
#include <hip/hip_runtime.h>
#include <math.h>

#define B_  4
#define V_  256
#define C1_ 64
#define C2_ 32
#define H0_ 128
#define H2_ 256

typedef short bf16x8 __attribute__((ext_vector_type(8)));
typedef float f32x4  __attribute__((ext_vector_type(4)));

static __device__ __forceinline__ short f2bf(float f) {
    unsigned u = __float_as_uint(f);
    u += 0x7fffu + ((u >> 16) & 1u);          // RNE
    return (short)(u >> 16);
}

// ---------------------------------------------------------------------------
// Weight prep (runs every launch): transpose + bf16-convert the edge-part of
// W1 (W1c: [32][H0] -> [H0][32]) and W2 ([H0][H0] -> [H0][H0]^T) for both
// conv layers, so MFMA B-fragments are contiguous 16 B loads.
// Layout in wsW (shorts): W1cT1[128*32] | W2T1[128*128] | W1cT2 | W2T2
// ---------------------------------------------------------------------------
__global__ __launch_bounds__(256) void prep_k(
    const float* __restrict__ W1c1, const float* __restrict__ W21,
    const float* __restrict__ W1c2, const float* __restrict__ W22,
    short* __restrict__ wsW)
{
    int idx = blockIdx.x * 256 + threadIdx.x;        // 40960 total
    if (idx < 4096) {
        int n = idx >> 5, k = idx & 31;
        wsW[idx] = f2bf(W1c1[k * H0_ + n]);
    } else if (idx < 20480) {
        int t = idx - 4096; int n = t >> 7, k = t & 127;
        wsW[idx] = f2bf(W21[k * H0_ + n]);
    } else if (idx < 24576) {
        int t = idx - 20480; int n = t >> 5, k = t & 31;
        wsW[idx] = f2bf(W1c2[k * H0_ + n]);
    } else if (idx < 40960) {
        int t = idx - 24576; int n = t >> 7, k = t & 127;
        wsW[idx] = f2bf(W22[k * H0_ + n]);
    }
}

// ---------------------------------------------------------------------------
// Per-node hoist: P = x@(W1a-W1b)+b1, Q = x@W1b (fp32, unchanged)
// ---------------------------------------------------------------------------
template <int CIN>
__global__ __launch_bounds__(128) void node_pre_k(
    const float* __restrict__ x, const float* __restrict__ W1,
    const float* __restrict__ b1, float* __restrict__ P, float* __restrict__ Q)
{
    const int bi = blockIdx.x, n = threadIdx.x;
    __shared__ __align__(16) float s_x[CIN];
    if (n < CIN) s_x[n] = x[bi * CIN + n];
    __syncthreads();
    float accP = b1[n], accQ = 0.f;
    #pragma unroll 4
    for (int k = 0; k < CIN; k += 4) {
        float4 xv = *reinterpret_cast<const float4*>(&s_x[k]);
        float wa0 = W1[(k + 0) * H0_ + n], wb0 = W1[(CIN + k + 0) * H0_ + n];
        float wa1 = W1[(k + 1) * H0_ + n], wb1 = W1[(CIN + k + 1) * H0_ + n];
        float wa2 = W1[(k + 2) * H0_ + n], wb2 = W1[(CIN + k + 2) * H0_ + n];
        float wa3 = W1[(k + 3) * H0_ + n], wb3 = W1[(CIN + k + 3) * H0_ + n];
        accP = fmaf(xv.x, wa0 - wb0, accP);  accQ = fmaf(xv.x, wb0, accQ);
        accP = fmaf(xv.y, wa1 - wb1, accP);  accQ = fmaf(xv.y, wb1, accQ);
        accP = fmaf(xv.z, wa2 - wb2, accP);  accQ = fmaf(xv.z, wb2, accQ);
        accP = fmaf(xv.w, wa3 - wb3, accP);  accQ = fmaf(xv.w, wb3, accQ);
    }
    P[bi * H0_ + n] = accP;
    Q[bi * H0_ + n] = accQ;
}

// ---------------------------------------------------------------------------
// EdgeConvE main (R1-v2 structure + ballot list build).
// Block = node (b,i); 4 waves, each owns a 16-edge M-tile per 64-edge pass
// and all 128 output neurons for GEMM1.  GEMM2 is N-split across waves
// (B2 = 32 VGPRs/wave -> 4 blocks/CU occupancy).
// Neighbor list: wave-ballot + popcount prefix (was: 128 serialized LDS
// atomics on one address, ~2.5-5K wasted cycles at block head).
// ---------------------------------------------------------------------------
__global__ __launch_bounds__(256, 4) void conv_mfma_k(
    const int* __restrict__ adj, const float* __restrict__ e,
    const float* __restrict__ P, const float* __restrict__ Q,
    const short* __restrict__ W1cT, const short* __restrict__ W2T,
    const float* __restrict__ b2, float* __restrict__ out)
{
    const int bi   = blockIdx.x;           // b*V + i
    const int b    = bi >> 8;
    const int tid  = threadIdx.x;
    const int w    = tid >> 6;
    const int lane = tid & 63;
    const int l15  = lane & 15;
    const int quad = lane >> 4;

    __shared__ int s_list[V_];
    __shared__ int s_wc[4];
    __shared__ __align__(16) short s_h1[64][136];   // 272 B stride, 16B-aligned

    // ballot-based neighbor list (no atomics)
    const int av = adj[bi * V_ + tid];
    unsigned long long bm = __ballot(av > 0);
    if (lane == 0) s_wc[w] = __popcll(bm);
    __syncthreads();
    const int cnt = s_wc[0] + s_wc[1] + s_wc[2] + s_wc[3];
    if (av > 0) {
        int base = 0;
        #pragma unroll
        for (int k = 0; k < 4; ++k) if (k < w) base += s_wc[k];
        int pos = base + __popcll(bm & ((1ull << lane) - 1ull));
        s_list[pos] = tid;
    }
    __syncthreads();
    if (cnt == 0) { if (tid < H0_) out[bi * H0_ + tid] = 0.f; return; }

    // GEMM2 B-fragments: wave w owns N-tiles 2w, 2w+1 -> 8 frags (32 VGPR)
    bf16x8 B2[2][4];
    float bb[2], vmax[2];
    #pragma unroll
    for (int h = 0; h < 2; ++h) {
        const int nt = w * 2 + h;
        #pragma unroll
        for (int kk = 0; kk < 4; ++kk)
            B2[h][kk] = *(const bf16x8*)(W2T + (nt * 16 + l15) * H0_ + kk * 32 + quad * 8);
        bb[h]   = b2[nt * 16 + l15];
        vmax[h] = 0.f;
    }
    float Pp[8];
    #pragma unroll
    for (int nt = 0; nt < 8; ++nt) Pp[nt] = P[bi * H0_ + nt * 16 + l15];

    const int row0 = w * 16;

    // prefetch first pass's e rows
    int ta0 = row0 + l15; if (ta0 >= cnt) ta0 = cnt - 1;
    const float* er0 = e + (bi * V_ + s_list[ta0]) * C2_ + quad * 8;
    float4 e0 = *(const float4*)(er0);
    float4 e1 = *(const float4*)(er0 + 4);

    for (int t0 = 0; t0 < cnt; t0 += 64) {
        const int tb = t0 + row0;

        // A-fragment for GEMM1 from prefetched e: A[m=l15][k=quad*8+j]
        bf16x8 A1;
        A1[0] = f2bf(e0.x); A1[1] = f2bf(e0.y); A1[2] = f2bf(e0.z); A1[3] = f2bf(e0.w);
        A1[4] = f2bf(e1.x); A1[5] = f2bf(e1.y); A1[6] = f2bf(e1.z); A1[7] = f2bf(e1.w);

        // issue next pass's e loads now; they retire under GEMM1+GEMM2
        {
            int tn = t0 + 64 + row0 + l15; if (tn >= cnt) tn = cnt - 1;
            const float* ern = e + (bi * V_ + s_list[tn]) * C2_ + quad * 8;
            e0 = *(const float4*)(ern);
            e1 = *(const float4*)(ern + 4);
        }

        // GEMM1: e @ W1c (K=32, one MFMA per N-tile; B1 from L1-resident global)
        f32x4 acc[8];
        #pragma unroll
        for (int nt = 0; nt < 8; ++nt) {
            bf16x8 B1 = *(const bf16x8*)(W1cT + (nt * 16 + l15) * C2_ + quad * 8);
            f32x4 z = {0.f, 0.f, 0.f, 0.f};
            acc[nt] = __builtin_amdgcn_mfma_f32_16x16x32_bf16(A1, B1, z, 0, 0, 0);
        }

        // make sure previous pass's GEMM2 readers are done before overwriting
        if (t0 > 0) __syncthreads();

        // epilogue 1: + P[i] + Q[j], relu, bf16 -> LDS (rows = edge slots)
        #pragma unroll
        for (int r = 0; r < 4; ++r) {
            int t = tb + quad * 4 + r; if (t >= cnt) t = cnt - 1;
            const float* Qr = Q + (b * V_ + s_list[t]) * H0_ + l15;
            short* dst = &s_h1[row0 + quad * 4 + r][l15];
            #pragma unroll
            for (int nt = 0; nt < 8; ++nt) {
                float v = acc[nt][r] + Pp[nt] + Qr[nt * 16];
                dst[nt * 16] = f2bf(fmaxf(v, 0.f));
            }
        }

        __syncthreads();

        // GEMM2: h1 @ W2, N-split across waves, M = all 64 edge rows
        #pragma unroll
        for (int mt = 0; mt < 4; ++mt) {
            f32x4 a20 = {0.f,0.f,0.f,0.f}, a21 = {0.f,0.f,0.f,0.f};
            #pragma unroll
            for (int kk = 0; kk < 4; ++kk) {
                bf16x8 A2 = *(const bf16x8*)(&s_h1[mt * 16 + l15][kk * 32 + quad * 8]);
                a20 = __builtin_amdgcn_mfma_f32_16x16x32_bf16(A2, B2[0][kk], a20, 0, 0, 0);
                a21 = __builtin_amdgcn_mfma_f32_16x16x32_bf16(A2, B2[1][kk], a21, 0, 0, 0);
            }
            float m0 = fmaxf(fmaxf(a20[0], a20[1]), fmaxf(a20[2], a20[3]));
            float m1 = fmaxf(fmaxf(a21[0], a21[1]), fmaxf(a21[2], a21[3]));
            vmax[0] = fmaxf(vmax[0], fmaxf(m0 + bb[0], 0.f));
            vmax[1] = fmaxf(vmax[1], fmaxf(m1 + bb[1], 0.f));
        }
    }

    // cross-quad (rows) max, then direct write of this wave's own channels
    #pragma unroll
    for (int h = 0; h < 2; ++h) {
        float p = vmax[h];
        p = fmaxf(p, __shfl_xor(p, 16, 64));
        p = fmaxf(p, __shfl_xor(p, 32, 64));
        if (quad == 0) out[bi * H0_ + (w * 2 + h) * 16 + l15] = p;
    }
}

// ---------------------------------------------------------------------------
// Pair hoist (fp32, unchanged): Ai = x2@W3[H0:]+b3, Aj = x2@W3[:H0]
// ---------------------------------------------------------------------------
__global__ __launch_bounds__(256) void pair_pre_k(
    const float* __restrict__ x2, const float* __restrict__ W3,
    const float* __restrict__ b3, float* __restrict__ Ai, float* __restrict__ Aj)
{
    const int bi = blockIdx.x, n = threadIdx.x;
    __shared__ __align__(16) float s_x[H0_];
    if (n < H0_) s_x[n] = x2[bi * H0_ + n];
    __syncthreads();
    float aI = b3[n], aJ = 0.f;
    #pragma unroll 4
    for (int k = 0; k < H0_; k += 4) {
        float4 xv = *reinterpret_cast<const float4*>(&s_x[k]);
        aJ = fmaf(xv.x, W3[(k + 0) * H2_ + n], aJ);
        aJ = fmaf(xv.y, W3[(k + 1) * H2_ + n], aJ);
        aJ = fmaf(xv.z, W3[(k + 2) * H2_ + n], aJ);
        aJ = fmaf(xv.w, W3[(k + 3) * H2_ + n], aJ);
        aI = fmaf(xv.x, W3[(H0_ + k + 0) * H2_ + n], aI);
        aI = fmaf(xv.y, W3[(H0_ + k + 1) * H2_ + n], aI);
        aI = fmaf(xv.z, W3[(H0_ + k + 2) * H2_ + n], aI);
        aI = fmaf(xv.w, W3[(H0_ + k + 3) * H2_ + n], aI);
    }
    Ai[bi * H2_ + n] = aI;
    Aj[bi * H2_ + n] = aJ;
}

// ---------------------------------------------------------------------------
// Pair output v4: block = (b, 4 consecutive i, 32-j tile); grid 2048.
// The block's Aj tile (32 rows x 256 ch = 32 KB) is staged ONCE in LDS
// (cooperative coalesced load) instead of each of 4 waves re-gathering it
// from L2 (268 MB -> 67 MB L2 traffic; ~7.8 us L2-BW floor removed).
// LDS layout: float4-swizzled  idx = jr*64 + (f ^ (jr&7))  -> each lane
// group's 64B-strided chunks land on all 8 bank-groups (b128 wave64 floor).
// ---------------------------------------------------------------------------
__global__ __launch_bounds__(256) void pair_out_k(
    const float* __restrict__ Ai, const float* __restrict__ Aj,
    const float* __restrict__ Wo, const float* __restrict__ bo,
    float* __restrict__ out)
{
    const int blk  = blockIdx.x;                       // 2048 blocks
    const int b    = blk >> 9;
    const int ig   = (blk >> 3) & 63;
    const int jq   = blk & 7;                          // 8 tiles of 32 j
    const int i    = (ig << 2) + (threadIdx.x >> 6);
    const int lane = threadIdx.x & 63;
    const int jj   = lane >> 4;
    const int c    = lane & 15;

    __shared__ __align__(16) float4 s_aj[32 * 64];     // 32 KB, swizzled

    // cooperative stage: 32 rows x 64 float4 (coalesced; write = row-perm)
    const float4* src = (const float4*)(Aj + (b * V_ + jq * 32) * H2_);
    #pragma unroll
    for (int k = 0; k < 8; ++k) {
        int g  = threadIdx.x + k * 256;
        int jr = g >> 6, f = g & 63;
        s_aj[jr * 64 + (f ^ (jr & 7))] = src[g];
    }

    const float* ai = Ai + (b * V_ + i) * H2_ + c * 16;
    float4 a0 = *(const float4*)(ai);
    float4 a1 = *(const float4*)(ai + 4);
    float4 a2 = *(const float4*)(ai + 8);
    float4 a3 = *(const float4*)(ai + 12);
    const float* wo = Wo + c * 16;
    float4 w0 = *(const float4*)(wo);
    float4 w1 = *(const float4*)(wo + 4);
    float4 w2 = *(const float4*)(wo + 8);
    float4 w3 = *(const float4*)(wo + 12);
    const float bo0 = bo[0];

    __syncthreads();

    for (int js = 0; js < 32; js += 4) {
        const int jr = js + jj;
        const float4* arow = &s_aj[jr * 64];
        const int sw = jr & 7, f0 = c * 4;
        float4 q0 = arow[(f0 + 0) ^ sw];
        float4 q1 = arow[(f0 + 1) ^ sw];
        float4 q2 = arow[(f0 + 2) ^ sw];
        float4 q3 = arow[(f0 + 3) ^ sw];
        float p;
        p = fmaxf(a0.x + q0.x, 0.f) * w0.x;
        p = fmaf(fmaxf(a0.y + q0.y, 0.f), w0.y, p);
        p = fmaf(fmaxf(a0.z + q0.z, 0.f), w0.z, p);
        p = fmaf(fmaxf(a0.w + q0.w, 0.f), w0.w, p);
        p = fmaf(fmaxf(a1.x + q1.x, 0.f), w1.x, p);
        p = fmaf(fmaxf(a1.y + q1.y, 0.f), w1.y, p);
        p = fmaf(fmaxf(a1.z + q1.z, 0.f), w1.z, p);
        p = fmaf(fmaxf(a1.w + q1.w, 0.f), w1.w, p);
        p = fmaf(fmaxf(a2.x + q2.x, 0.f), w2.x, p);
        p = fmaf(fmaxf(a2.y + q2.y, 0.f), w2.y, p);
        p = fmaf(fmaxf(a2.z + q2.z, 0.f), w2.z, p);
        p = fmaf(fmaxf(a2.w + q2.w, 0.f), w2.w, p);
        p = fmaf(fmaxf(a3.x + q3.x, 0.f), w3.x, p);
        p = fmaf(fmaxf(a3.y + q3.y, 0.f), w3.y, p);
        p = fmaf(fmaxf(a3.z + q3.z, 0.f), w3.z, p);
        p = fmaf(fmaxf(a3.w + q3.w, 0.f), w3.w, p);
        #pragma unroll
        for (int off = 1; off < 16; off <<= 1)
            p += __shfl_xor(p, off, 64);               // stays within jj group
        if (c == 0)
            out[(b * V_ + i) * V_ + jq * 32 + jr] =
                1.f / (1.f + __builtin_expf(-(p + bo0)));
    }
}

// ---------------------------------------------------------------------------
extern "C" void kernel_launch(void* const* d_in, const int* in_sizes, int n_in,
                              void* d_out, int out_size, void* d_ws, size_t ws_size,
                              hipStream_t stream) {
    const int*   adj   = (const int*)  d_in[0];
    const float* xf    = (const float*)d_in[1];
    const float* ea    = (const float*)d_in[2];
    const float* ec1W1 = (const float*)d_in[3];
    const float* ec1b1 = (const float*)d_in[4];
    const float* ec1W2 = (const float*)d_in[5];
    const float* ec1b2 = (const float*)d_in[6];
    const float* ec2W1 = (const float*)d_in[7];
    const float* ec2b1 = (const float*)d_in[8];
    const float* ec2W2 = (const float*)d_in[9];
    const float* ec2b2 = (const float*)d_in[10];
    const float* h3W   = (const float*)d_in[11];
    const float* h3b   = (const float*)d_in[12];
    const float* oW    = (const float*)d_in[13];
    const float* ob    = (const float*)d_in[14];
    float* out = (float*)d_out;

    const int NV = B_ * V_;                    // 1024 nodes
    float* x1 = (float*)d_ws;                  // NV*H0
    float* x2 = x1 + NV * H0_;                 // NV*H0
    float* R  = x2 + NV * H0_;                 // reuse region
    float* P  = R;                             // NV*H0
    float* Q  = R + NV * H0_;                  // NV*H0
    float* Ai = R;                             // NV*H2 (P/Q dead by then)
    float* Aj = R + NV * H2_;                  // NV*H2
    short* wsW = (short*)(R + 2 * NV * H2_);   // 40960 bf16 weights
    short* W1cT1 = wsW;
    short* W2T1  = wsW + 4096;
    short* W1cT2 = wsW + 20480;
    short* W2T2  = wsW + 24576;

    prep_k<<<160, 256, 0, stream>>>(ec1W1 + 2 * C1_ * H0_, ec1W2,
                                    ec2W1 + 2 * H0_ * H0_, ec2W2, wsW);
    // conv1
    node_pre_k<C1_><<<NV, 128, 0, stream>>>(xf, ec1W1, ec1b1, P, Q);
    conv_mfma_k<<<NV, 256, 0, stream>>>(adj, ea, P, Q, W1cT1, W2T1, ec1b2, x1);
    // conv2
    node_pre_k<H0_><<<NV, 128, 0, stream>>>(x1, ec2W1, ec2b1, P, Q);
    conv_mfma_k<<<NV, 256, 0, stream>>>(adj, ea, P, Q, W1cT2, W2T2, ec2b2, x2);
    // pair scoring
    pair_pre_k<<<NV, 256, 0, stream>>>(x2, h3W, h3b, Ai, Aj);
    pair_out_k<<<2048, 256, 0, stream>>>(Ai, Aj, oW, ob, out);
}